// Round 6
// baseline (623.064 us; speedup 1.0000x reference)
//
#include <hip/hip_runtime.h>

// snn_layer: out[b,u,t] = (sum_f in[b,f,t] * w[f,u] > 1.0f) ? 1.0f : 0.0f
// B=128 F=512 T=256 U=1024, fp32 in/out.
//
// fp32 has no MFMA on CDNA4 -> exact bf16 hi/lo split, 3-pass MFMA:
//   h ~= Ah*Bh + Ah*Bl + Al*Bh   (error ~1e-5; threshold band |h-1|<=1e-3
// recomputed in fp32 with the verified sequential-fmaf order -> flip-free).
//
// Round-6: rounds 4/5 (counted-vmcnt + raw s_barrier + global_load_lds)
// killed the container twice -> per the pre-committed decision rule, pivot
// to a barrier-free structure. Round-2 evidence: per block-chunk ~6100 cyc
// vs ~1100 useful; the stage->drain(vmcnt0)->compute serialization exposes
// full memory latency each chunk and makes MLP bursty (realized 1.6 TB/s,
// nothing saturated).
//
// Fix: NO LDS in the main kernel at all. ws operands are k-contiguous
// [row][f], so each lane's MFMA fragment is a direct 16-B global load
// (row = wm+i*16+lr, kseg = lq*8). Wave coalescing: lanes {r,r+16,r+32,
// r+48} cover 64 contiguous bytes of row r -> 16 full 64-B lines per
// instruction. Zero barriers -> waves flow continuously; 12 waves/CU
// (LDS=0, ~150 VGPR @ launch_bounds(256,3)) sustain MLP; compiler inserts
// its own counted vmcnt before each fragment use. A/B-half duplication
// between wave pairs is absorbed by L1 (4 KB/half/chunk << 32 KB).
// Fragment bytes + MFMA order bit-identical to verified rounds -> absmax 0.

#define BB 128
#define FF 512
#define TT 256
#define UU 1024

typedef float v4f __attribute__((ext_vector_type(4)));
typedef short v8s __attribute__((ext_vector_type(8)));
typedef unsigned short v8us __attribute__((ext_vector_type(8)));

__device__ __forceinline__ unsigned short bf16rn(float x) {
    unsigned u = __float_as_uint(x);
    u = u + 0x7FFFu + ((u >> 16) & 1u);   // round-to-nearest-even
    return (unsigned short)(u >> 16);
}
__device__ __forceinline__ float bf16tof(unsigned short h) {
    return __uint_as_float(((unsigned)h) << 16);
}

// ---------------------------------------------------------------------------
// Prepass: transpose + hi/lo split (unchanged, verified).
// Panels of 512(f) x 256(cols): z<128 -> X batch z (row stride TT);
// z in [128,132) -> W column-strip s=z-128 (row stride UU).
// Output row-major [col][f], f contiguous (512 bf16 = 1024 B rows).
// ---------------------------------------------------------------------------
__global__ __launch_bounds__(256)
void prepass_kernel(const float* __restrict__ in, const float* __restrict__ w,
                    unsigned short* __restrict__ xth, unsigned short* __restrict__ xtl,
                    unsigned short* __restrict__ wth, unsigned short* __restrict__ wtl) {
    __shared__ float Ls[64][65];

    const int z = blockIdx.z;
    const float* src;
    int srow;
    unsigned short *dh, *dl;
    if (z < BB) {
        src = in + (size_t)z * FF * TT;  srow = TT;
        dh = xth + (size_t)z * TT * FF;  dl = xtl + (size_t)z * TT * FF;
    } else {
        const int s = z - BB;
        src = w + s * 256;               srow = UU;
        dh = wth + (size_t)s * 256 * FF; dl = wtl + (size_t)s * 256 * FF;
    }
    const int f0 = blockIdx.y * 64;
    const int c0 = blockIdx.x * 64;
    const int tid = threadIdx.x;
    const int r  = tid >> 4;
    const int c4 = (tid & 15) * 4;

#pragma unroll
    for (int i = 0; i < 4; i++) {
        const float4 v = *(const float4*)&src[(size_t)(f0 + r + 16 * i) * srow + c0 + c4];
        Ls[r + 16 * i][c4 + 0] = v.x;
        Ls[r + 16 * i][c4 + 1] = v.y;
        Ls[r + 16 * i][c4 + 2] = v.z;
        Ls[r + 16 * i][c4 + 3] = v.w;
    }
    __syncthreads();

#pragma unroll
    for (int i = 0; i < 2; i++) {
        const int orow = 32 * i + (tid >> 3);
        const int fs   = (tid & 7) * 8;
        v8us hp, lp;
#pragma unroll
        for (int k = 0; k < 8; k++) {
            const float a = Ls[fs + k][orow];
            const unsigned short h = bf16rn(a);
            hp[k] = h;
            lp[k] = bf16rn(a - bf16tof(h));
        }
        const size_t o = (size_t)(c0 + orow) * FF + f0 + fs;
        *(v8us*)&dh[o] = hp;
        *(v8us*)&dl[o] = lp;
    }
}

// ---------------------------------------------------------------------------
// Main MFMA GEMM, LDS-free / barrier-free. 128x128 tile, 4 waves (2x2 of
// 64x64), BK=32 per chunk. Fragments loaded straight from the k-contiguous
// ws arrays: 16 x global_load_dwordx4 + 48 MFMAs per chunk per wave.
// ---------------------------------------------------------------------------
__global__ __launch_bounds__(256, 3)
void snn_mfma_kernel(const unsigned short* __restrict__ wth,
                     const unsigned short* __restrict__ wtl,
                     const unsigned short* __restrict__ xth,
                     const unsigned short* __restrict__ xtl,
                     const float* __restrict__ in, const float* __restrict__ w,
                     float* __restrict__ out) {
    // XCD-chunked, b-major swizzle (proven: FETCH 507->390 MB).
    const int h = blockIdx.x;
    const int l = ((h & 7) << 8) | (h >> 3);
    const int b  = l >> 4;
    const int u0 = ((l >> 1) & 7) * 128;
    const int t0 = (l & 1) * 128;

    const int tid = threadIdx.x;
    const int wv  = tid >> 6;        // wave 0..3
    const int ln  = tid & 63;
    const int lr  = ln & 15;         // fragment m/n index
    const int lq  = ln >> 4;         // fragment k-quad
    const int wm  = (wv & 1) * 64;   // wave tile origin (u)
    const int wn  = (wv >> 1) * 64;  // wave tile origin (t)

    // Per-lane fragment base pointers (elements). Row stride FF=512 elem.
    // Fragment i lives at base + i*16*FF + c*32 (chunk c), 16-B aligned.
    const unsigned short* __restrict__ ah_p =
        wth + (size_t)(u0 + wm + lr) * FF + lq * 8;
    const unsigned short* __restrict__ al_p =
        wtl + (size_t)(u0 + wm + lr) * FF + lq * 8;
    const unsigned short* __restrict__ bh_p =
        xth + ((size_t)b * TT + t0 + wn + lr) * FF + lq * 8;
    const unsigned short* __restrict__ bl_p =
        xtl + ((size_t)b * TT + t0 + wn + lr) * FF + lq * 8;

    v4f acc[4][4];
#pragma unroll
    for (int i = 0; i < 4; i++)
#pragma unroll
        for (int j = 0; j < 4; j++) {
            v4f zz = {0.0f, 0.0f, 0.0f, 0.0f};
            acc[i][j] = zz;
        }

#pragma unroll 1
    for (int c = 0; c < 16; c++) {
        const int fk = c * 32;       // k-offset of this chunk
        v8s ah[4], al[4], bh[4], bl[4];
#pragma unroll
        for (int i = 0; i < 4; i++) {
            ah[i] = *(const v8s*)&ah_p[i * 16 * FF + fk];
            al[i] = *(const v8s*)&al_p[i * 16 * FF + fk];
        }
#pragma unroll
        for (int j = 0; j < 4; j++) {
            bh[j] = *(const v8s*)&bh_p[j * 16 * FF + fk];
            bl[j] = *(const v8s*)&bl_p[j * 16 * FF + fk];
        }
#pragma unroll
        for (int i = 0; i < 4; i++)
#pragma unroll
            for (int j = 0; j < 4; j++) {
                acc[i][j] = __builtin_amdgcn_mfma_f32_16x16x32_bf16(ah[i], bh[j], acc[i][j], 0, 0, 0);
                acc[i][j] = __builtin_amdgcn_mfma_f32_16x16x32_bf16(ah[i], bl[j], acc[i][j], 0, 0, 0);
                acc[i][j] = __builtin_amdgcn_mfma_f32_16x16x32_bf16(al[i], bh[j], acc[i][j], 0, 0, 0);
            }
    }

    // Epilogue. C/D layout: col = lane&15, row = (lane>>4)*4+reg.
    const float* xb   = in  + (size_t)b * FF * TT;
    float* __restrict__ outb = out + (size_t)b * UU * TT;
#pragma unroll
    for (int i = 0; i < 4; i++) {
#pragma unroll
        for (int r = 0; r < 4; r++) {
            const int u = u0 + wm + i * 16 + lq * 4 + r;
#pragma unroll
            for (int j = 0; j < 4; j++) {
                const int t = t0 + wn + j * 16 + lr;
                float hh = acc[i][j][r];
                if (__builtin_expect(__builtin_fabsf(hh - 1.0f) <= 1e-3f, 0)) {
                    // exact fp32 recompute: identical sequential fmaf order
                    // (f ascending from 0) as the verified fp32 kernel.
                    float s2 = 0.0f;
                    const float* wp = w  + u;
                    const float* xp = xb + t;
#pragma unroll 16
                    for (int f = 0; f < FF; f++)
                        s2 = fmaf(wp[(size_t)f * UU], xp[(size_t)f * TT], s2);
                    hh = s2;
                }
                outb[(size_t)u * TT + t] = hh > 1.0f ? 1.0f : 0.0f;
            }
        }
    }
}

// ---------------------------------------------------------------------------
// Fallback: previous verified fp32 vector-FMA kernel (used if ws too small).
// ---------------------------------------------------------------------------
__global__ __launch_bounds__(256, 4)
void snn_gemm_kernel(const float* __restrict__ in, const float* __restrict__ w,
                     float* __restrict__ out) {
    __shared__ float As[16][128];
    __shared__ float Bs[16][128];

    const int b  = blockIdx.z;
    const int u0 = blockIdx.y * 128;
    const int t0 = blockIdx.x * 128;

    const float* __restrict__ inb  = in  + (size_t)b * FF * TT;
    float* __restrict__       outb = out + (size_t)b * UU * TT;

    const int tid = threadIdx.x;
    const int tx  = tid & 15;
    const int ty  = tid >> 4;

    const int k0 = tid >> 5;
    const int c0 = (tid & 31) * 4;
    const int k1 = k0 + 8;

    float acc[8][8];
#pragma unroll
    for (int i = 0; i < 8; i++)
#pragma unroll
        for (int j = 0; j < 8; j++) acc[i][j] = 0.0f;

    float4 a_r0 = *(const float4*)&w[(size_t)k0 * UU + u0 + c0];
    float4 a_r1 = *(const float4*)&w[(size_t)k1 * UU + u0 + c0];
    float4 b_r0 = *(const float4*)&inb[k0 * TT + t0 + c0];
    float4 b_r1 = *(const float4*)&inb[k1 * TT + t0 + c0];

    for (int f0 = 0; f0 < FF; f0 += 16) {
        *(float4*)&As[k0][c0] = a_r0;
        *(float4*)&As[k1][c0] = a_r1;
        *(float4*)&Bs[k0][c0] = b_r0;
        *(float4*)&Bs[k1][c0] = b_r1;
        __syncthreads();

        if (f0 + 16 < FF) {
            const int fn = f0 + 16;
            a_r0 = *(const float4*)&w[(size_t)(fn + k0) * UU + u0 + c0];
            a_r1 = *(const float4*)&w[(size_t)(fn + k1) * UU + u0 + c0];
            b_r0 = *(const float4*)&inb[(fn + k0) * TT + t0 + c0];
            b_r1 = *(const float4*)&inb[(fn + k1) * TT + t0 + c0];
        }

#pragma unroll
        for (int k = 0; k < 16; k++) {
            const float4 a0 = *(const float4*)&As[k][ty * 4];
            const float4 a1 = *(const float4*)&As[k][ty * 4 + 64];
            const float4 v0 = *(const float4*)&Bs[k][tx * 4];
            const float4 v1 = *(const float4*)&Bs[k][tx * 4 + 64];
            const float am[8] = {a0.x, a0.y, a0.z, a0.w, a1.x, a1.y, a1.z, a1.w};
            const float bn[8] = {v0.x, v0.y, v0.z, v0.w, v1.x, v1.y, v1.z, v1.w};
#pragma unroll
            for (int i = 0; i < 8; i++)
#pragma unroll
                for (int j = 0; j < 8; j++)
                    acc[i][j] = fmaf(am[i], bn[j], acc[i][j]);
        }
        __syncthreads();
    }

#pragma unroll
    for (int i = 0; i < 8; i++) {
        const int m = (i < 4) ? (ty * 4 + i) : (64 + ty * 4 + i - 4);
        float* __restrict__ orow = outb + (size_t)(u0 + m) * TT + t0;
        float4 o0, o1;
        o0.x = acc[i][0] > 1.0f ? 1.0f : 0.0f;
        o0.y = acc[i][1] > 1.0f ? 1.0f : 0.0f;
        o0.z = acc[i][2] > 1.0f ? 1.0f : 0.0f;
        o0.w = acc[i][3] > 1.0f ? 1.0f : 0.0f;
        o1.x = acc[i][4] > 1.0f ? 1.0f : 0.0f;
        o1.y = acc[i][5] > 1.0f ? 1.0f : 0.0f;
        o1.z = acc[i][6] > 1.0f ? 1.0f : 0.0f;
        o1.w = acc[i][7] > 1.0f ? 1.0f : 0.0f;
        *(float4*)&orow[tx * 4]      = o0;
        *(float4*)&orow[tx * 4 + 64] = o1;
    }
}

extern "C" void kernel_launch(void* const* d_in, const int* in_sizes, int n_in,
                              void* d_out, int out_size, void* d_ws, size_t ws_size,
                              hipStream_t stream) {
    const float* in = (const float*)d_in[0];  // [128,512,256]
    const float* w  = (const float*)d_in[1];  // [512,1024]
    float* out      = (float*)d_out;          // [128,1024,256]

    const size_t XN  = (size_t)BB * TT * FF;
    const size_t WN  = (size_t)UU * FF;
    const size_t NEED = (2 * XN + 2 * WN) * sizeof(unsigned short);

    if (ws_size >= NEED) {
        unsigned short* xth = (unsigned short*)d_ws;
        unsigned short* xtl = xth + XN;
        unsigned short* wth = xtl + XN;
        unsigned short* wtl = wth + WN;
        prepass_kernel<<<dim3(4, 8, 132), dim3(256), 0, stream>>>(in, w, xth, xtl, wth, wtl);
        snn_mfma_kernel<<<dim3(2048), dim3(256), 0, stream>>>(
            wth, wtl, xth, xtl, in, w, out);
    } else {
        snn_gemm_kernel<<<dim3(TT / 128, UU / 128, BB), dim3(256), 0, stream>>>(in, w, out);
    }
}